// Round 12
// baseline (349.147 us; speedup 1.0000x reference)
//
#include <hip/hip_runtime.h>
#include <hip/hip_bf16.h>

#define NN 50000
#define NE 1200000
#define D 64
#define NEG_SLOPE 0.2f
#define EPS_SM 1e-16f
#define EPS_LN 1e-5f
#define KMAX 4            // supports degree <= 256; Poisson(24) max over 50k nodes ~55
#define BSH 6             // 64 nodes per bucket
#define NBUK 782          // ceil(50000/64)
#define BCAP 2048         // fixed bucket capacity (mean 1536, +13 sigma)
#define BCAPSH 11
#define EPB 4096          // edges per partition block
#define NPB 293           // ceil(NE/EPB)
#define GEMM_BLOCKS 3125  // NN/16 exactly
#define GAT_BLOCKS 12500  // NN/4 exactly

typedef __attribute__((ext_vector_type(8))) short short8;
typedef __attribute__((ext_vector_type(4))) float float4v;

__device__ __forceinline__ float waveReduceSum(float v) {
    #pragma unroll
    for (int off = 32; off > 0; off >>= 1)
        v += __shfl_xor(v, off, 64);
    return v;
}
__device__ __forceinline__ float waveReduceMax(float v) {
    #pragma unroll
    for (int off = 32; off > 0; off >>= 1)
        v = fmaxf(v, __shfl_xor(v, off, 64));
    return v;
}
__device__ __forceinline__ float bflo(unsigned v) { return __uint_as_float(v << 16); }
__device__ __forceinline__ float bfhi(unsigned v) { return __uint_as_float(v & 0xffff0000u); }
__device__ __forceinline__ short f2bf_bits(float f) {
    __hip_bfloat16 b = __float2bfloat16(f);
    short v; __builtin_memcpy(&v, &b, 2);
    return v;
}

// ---------------------------------------------------------------------------
// Pack W (fp32 64x64 mats, concatenated channels) into bf16 B-fragment order.
// ---------------------------------------------------------------------------
__global__ void pack_w(const float* __restrict__ W0,
                       const float* __restrict__ W1m,
                       const float* __restrict__ W2m,
                       unsigned short* __restrict__ wpk, int nmats) {
    const int n = nmats * 4096;
    for (int idx = blockIdx.x * 256 + threadIdx.x; idx < n; idx += gridDim.x * 256) {
        const int j = idx & 7;
        const int lane = (idx >> 3) & 63;
        const int khtile = idx >> 9;
        const int kh = khtile & 1;
        const int tile = khtile >> 1;
        const int mat = tile >> 2;
        const int ch = (tile & 3) * 16 + (lane & 15);
        const int k = kh * 32 + (lane >> 4) * 8 + j;
        const float* W = (mat == 0) ? W0 : (mat == 1 ? W1m : W2m);
        wpk[idx] = (unsigned short)f2bf_bits(W[k * D + ch]);
    }
}

// ---------------------------------------------------------------------------
// MFMA projections: block = 16 nodes, A = X-tile (LDS, cvt to bf16 frags),
// B = pre-packed W frags. Epilogue: hp/agg stores + alpha dot-products.
// ---------------------------------------------------------------------------
template <int NMATS>
__global__ __launch_bounds__(256) void gemm_mfma(
                          const float* __restrict__ hin,
                          const unsigned short* __restrict__ wpk,
                          const float* __restrict__ avs,
                          const float* __restrict__ avd,
                          const float* __restrict__ bgat,
                          const float* __restrict__ blin,
                          __hip_bfloat16* __restrict__ hp,
                          float* __restrict__ agg,
                          float* __restrict__ alpha_s,
                          float* __restrict__ alpha_d) {
    constexpr int NT   = NMATS * 4;
    constexpr int NTPW = NT / 4;
    __shared__ float xt[16 * D];           // 4 KB
    __shared__ float ared[2][4][16];       // alpha partials [s/d][wave][node]

    const int t   = threadIdx.x;
    const int nb0 = blockIdx.x * 16;       // 3125*16 == 50000 exactly
    ((float4*)xt)[t] = ((const float4*)(hin + (size_t)nb0 * D))[t];
    __syncthreads();

    const int w    = t >> 6;
    const int lane = t & 63;
    const int mrow = lane & 15;            // A row within tile
    const int kq   = lane >> 4;            // quad

    short8 a[2];
    #pragma unroll
    for (int kh = 0; kh < 2; ++kh) {
        const float* xp = xt + mrow * D + kh * 32 + kq * 8;
        const float4 f0 = *(const float4*)(xp);
        const float4 f1 = *(const float4*)(xp + 4);
        a[kh][0] = f2bf_bits(f0.x); a[kh][1] = f2bf_bits(f0.y);
        a[kh][2] = f2bf_bits(f0.z); a[kh][3] = f2bf_bits(f0.w);
        a[kh][4] = f2bf_bits(f1.x); a[kh][5] = f2bf_bits(f1.y);
        a[kh][6] = f2bf_bits(f1.z); a[kh][7] = f2bf_bits(f1.w);
    }

    float4v acc[NTPW];
    #pragma unroll
    for (int i = 0; i < NTPW; ++i) {
        const int tile = w * NTPW + i;
        const short8 b0 = *(const short8*)(wpk + ((size_t)(tile * 2 + 0) * 64 + lane) * 8);
        const short8 b1 = *(const short8*)(wpk + ((size_t)(tile * 2 + 1) * 64 + lane) * 8);
        float4v c = {0.f, 0.f, 0.f, 0.f};
        c = __builtin_amdgcn_mfma_f32_16x16x32_bf16(a[0], b0, c, 0, 0, 0);
        c = __builtin_amdgcn_mfma_f32_16x16x32_bf16(a[1], b1, c, 0, 0, 0);
        acc[i] = c;
    }

    float psr[4] = {0.f, 0.f, 0.f, 0.f};
    float pdr[4] = {0.f, 0.f, 0.f, 0.f};
    #pragma unroll
    for (int i = 0; i < NTPW; ++i) {
        const int tile = w * NTPW + i;
        const int mat  = tile >> 2;                 // wave-uniform
        const int c64  = (tile & 3) * 16 + mrow;
        const float av_s = avs[c64], av_d = avd[c64];
        const float bias = blin[c64] + bgat[c64];
        #pragma unroll
        for (int r = 0; r < 4; ++r) {
            const int node = nb0 + kq * 4 + r;      // C/D: col=lane&15, row=quad*4+reg
            const float v = acc[i][r];
            if (mat == 0) {
                hp[(size_t)node * D + c64] = __float2bfloat16(v);
                psr[r] += v * av_s;
                if (NMATS == 2) pdr[r] += v * av_d;
            } else if (NMATS == 3 && mat == 1) {
                pdr[r] += v * av_d;
            } else {
                agg[(size_t)node * D + c64] = v + bias;
            }
        }
    }
    #pragma unroll
    for (int off = 1; off < 16; off <<= 1) {
        #pragma unroll
        for (int r = 0; r < 4; ++r) {
            psr[r] += __shfl_xor(psr[r], off, 64);
            pdr[r] += __shfl_xor(pdr[r], off, 64);
        }
    }
    if (mrow == 0) {
        #pragma unroll
        for (int r = 0; r < 4; ++r) {
            ared[0][w][kq * 4 + r] = psr[r];
            ared[1][w][kq * 4 + r] = pdr[r];
        }
    }
    __syncthreads();
    if (t < 16) {
        alpha_s[nb0 + t] = ared[0][0][t] + ared[0][1][t] + ared[0][2][t] + ared[0][3][t];
        alpha_d[nb0 + t] = ared[1][0][t] + ared[1][1][t] + ared[1][2][t] + ared[1][3][t];
    }
}

// ---------------------------------------------------------------------------
// CSR-by-destination: fixed-capacity bucket layout.
// ---------------------------------------------------------------------------
__global__ __launch_bounds__(256) void bucket_partition(const int* __restrict__ ei,
                                                        int* __restrict__ bcur,
                                                        int2* __restrict__ pairs) {
    __shared__ int h[NBUK];
    __shared__ int cur[NBUK];
    for (int i = threadIdx.x; i < NBUK; i += 256) h[i] = 0;
    __syncthreads();
    const int base = blockIdx.x * EPB;
    const int lim  = min(EPB, NE - base);
    for (int i = threadIdx.x; i < lim; i += 256)
        atomicAdd(&h[ei[NE + base + i] >> BSH], 1);
    __syncthreads();
    for (int i = threadIdx.x; i < NBUK; i += 256) {
        const int c = h[i];
        cur[i] = c ? atomicAdd(&bcur[i], c) : 0;
    }
    __syncthreads();
    for (int i = threadIdx.x; i < lim; i += 256) {
        const int s = ei[base + i];
        const int d = ei[NE + base + i];
        const int b = d >> BSH;
        const int pos = atomicAdd(&cur[b], 1);
        if (pos < BCAP) pairs[(b << BCAPSH) + pos] = make_int2(s, d);
    }
}

__global__ __launch_bounds__(256) void csr_finalize(const int2* __restrict__ pairs,
                                                    const int* __restrict__ bcur,
                                                    int* __restrict__ cnt,
                                                    int* __restrict__ row_start,
                                                    int* __restrict__ csr_src) {
    __shared__ int ncnt[64];
    __shared__ int lsrc[BCAP];
    const int t = threadIdx.x;
    const int b = blockIdx.x;
    const int beg = b << BCAPSH;
    const int m = min(bcur[b], BCAP);
    const int nbase = b << BSH;
    if (t < 64) ncnt[t] = 0;
    __syncthreads();
    for (int i = t; i < m; i += 256)
        atomicAdd(&ncnt[pairs[beg + i].y - nbase], 1);
    __syncthreads();
    if (t < 64) {
        const int v = ncnt[t];
        int inc = v;
        #pragma unroll
        for (int off = 1; off < 64; off <<= 1) {
            const int u = __shfl_up(inc, off, 64);
            if (t >= off) inc += u;
        }
        const int excl = inc - v;
        if (nbase + t < NN) {
            cnt[nbase + t] = v;
            row_start[nbase + t] = beg + excl;
        }
        ncnt[t] = excl;   // becomes bucket-local cursor
    }
    __syncthreads();
    for (int i = t; i < m; i += 256) {
        const int2 p = pairs[beg + i];
        const int pos = atomicAdd(&ncnt[p.y - nbase], 1);
        lsrc[pos] = p.x;
    }
    __syncthreads();
    for (int i = t; i < m; i += 256)
        csr_src[beg + i] = lsrc[i];
}

// ---------------------------------------------------------------------------
// Fused per-node GAT: softmax + aggregate in one pass.
// Aggregation layout: 16 lanes/edge, each lane loads uint2 = 4 bf16 channels
// -> 4 edges per wave-instruction (half the loop iterations of the 2-edge
// form, same gather bytes). Streaming accesses (csr, agg) use non-temporal
// hints so L2 keeps the 6.4 MB hp table hot.
// ---------------------------------------------------------------------------
template <bool DO_RELU, bool DO_STATS>
__global__ __launch_bounds__(256) void gat_node(
                         const int* __restrict__ csr_src,
                         const int* __restrict__ row_start,
                         const int* __restrict__ cnt,
                         const float* __restrict__ as,
                         const float* __restrict__ ad,
                         const __hip_bfloat16* __restrict__ hp,
                         float* __restrict__ agg,
                         float* __restrict__ partial) {
    __shared__ int2 esm[4][KMAX * 64];
    const int wv   = threadIdx.x >> 6;
    const int lane = threadIdx.x & 63;
    const int node = blockIdx.x * 4 + wv;   // NN == 4*GAT_BLOCKS: always valid
    const int snode = __builtin_amdgcn_readfirstlane(node);
    const int deg = cnt[snode];
    const int rs  = row_start[snode];
    const int es  = lane >> 4;              // edge slot 0..3
    const int c   = lane & 15;              // uint2 index (4 channels)
    float a0x = 0.f, a0y = 0.f, a0z = 0.f, a0w = 0.f;
    float a1x = 0.f, a1y = 0.f, a1z = 0.f, a1w = 0.f;
    if (deg > 0) {
        const float ad_d = ad[snode];
        int   sr[KMAX];
        float ea[KMAX];
        float mx = -INFINITY;
        #pragma unroll
        for (int k = 0; k < KMAX; ++k) {
            const int j = k * 64 + lane;
            const bool valid = j < deg;
            const int s = valid ? __builtin_nontemporal_load(csr_src + rs + j) : 0;
            float a = valid ? (as[s] + ad_d) : -INFINITY;
            a = (a >= 0.f) ? a : NEG_SLOPE * a;
            sr[k] = s;
            ea[k] = a;
            mx = fmaxf(mx, a);
        }
        mx = waveReduceMax(mx);
        float sum = 0.f;
        #pragma unroll
        for (int k = 0; k < KMAX; ++k) {
            float e = __expf(ea[k] - mx);
            e = (k * 64 + lane < deg) ? e : 0.f;   // invalid lanes -> w = 0 (pads)
            ea[k] = e;
            sum += e;
        }
        sum = waveReduceSum(sum);
        const float inv = 1.f / (sum + EPS_SM);
        #pragma unroll
        for (int k = 0; k < KMAX; ++k) {
            if (k * 64 < deg)            // wave-uniform; lanes >= deg write {0,0}
                esm[wv][k * 64 + lane] = make_int2(sr[k] * 16, __float_as_int(ea[k] * inv));
        }
        // same-wave LDS write->read: compiler orders via lgkmcnt
        const uint2* hp64 = (const uint2*)hp;
        const int jmax = (deg + 3) & ~3;
        int j = 0;
        for (; j + 8 <= jmax; j += 8) {
            const int2 p0 = esm[wv][j + es];
            const int2 p1 = esm[wv][j + 4 + es];
            const uint2 v0 = hp64[p0.x + c];
            const uint2 v1 = hp64[p1.x + c];
            const float w0 = __int_as_float(p0.y), w1 = __int_as_float(p1.y);
            a0x = fmaf(w0, bflo(v0.x), a0x);
            a0y = fmaf(w0, bfhi(v0.x), a0y);
            a0z = fmaf(w0, bflo(v0.y), a0z);
            a0w = fmaf(w0, bfhi(v0.y), a0w);
            a1x = fmaf(w1, bflo(v1.x), a1x);
            a1y = fmaf(w1, bfhi(v1.x), a1y);
            a1z = fmaf(w1, bflo(v1.y), a1z);
            a1w = fmaf(w1, bfhi(v1.y), a1w);
        }
        for (; j < jmax; j += 4) {
            const int2 p = esm[wv][j + es];
            const uint2 v = hp64[p.x + c];
            const float w = __int_as_float(p.y);
            a0x = fmaf(w, bflo(v.x), a0x);
            a0y = fmaf(w, bfhi(v.x), a0y);
            a0z = fmaf(w, bflo(v.y), a0z);
            a0w = fmaf(w, bfhi(v.y), a0w);
        }
    }
    float rx = a0x + a1x, ry = a0y + a1y, rz = a0z + a1z, rw = a0w + a1w;
    #pragma unroll
    for (int off = 16; off <= 32; off <<= 1) {
        rx += __shfl_xor(rx, off, 64);
        ry += __shfl_xor(ry, off, 64);
        rz += __shfl_xor(rz, off, 64);
        rw += __shfl_xor(rw, off, 64);
    }

    float fx = 0.f, fy = 0.f, fz = 0.f, fw = 0.f;
    if (es == 0) {
        unsigned long long* ap = (unsigned long long*)(agg + (size_t)node * D + 4 * c);
        const unsigned long long g0 = __builtin_nontemporal_load(ap);
        const unsigned long long g1 = __builtin_nontemporal_load(ap + 1);
        fx = __uint_as_float((unsigned)g0) + rx;
        fy = __uint_as_float((unsigned)(g0 >> 32)) + ry;
        fz = __uint_as_float((unsigned)g1) + rz;
        fw = __uint_as_float((unsigned)(g1 >> 32)) + rw;
        if (DO_RELU) {
            fx = fmaxf(fx, 0.f); fy = fmaxf(fy, 0.f);
            fz = fmaxf(fz, 0.f); fw = fmaxf(fw, 0.f);
        }
        const unsigned long long o0 = (unsigned long long)__float_as_uint(fx) |
                                      ((unsigned long long)__float_as_uint(fy) << 32);
        const unsigned long long o1 = (unsigned long long)__float_as_uint(fz) |
                                      ((unsigned long long)__float_as_uint(fw) << 32);
        __builtin_nontemporal_store(o0, ap);
        __builtin_nontemporal_store(o1, ap + 1);
    }
    if (DO_STATS) {
        float s  = fx + fy + fz + fw;           // es != 0 lanes contribute 0
        float ss = fx * fx + fy * fy + fz * fz + fw * fw;
        s  = waveReduceSum(s);
        ss = waveReduceSum(ss);
        __shared__ float red[2][4];
        if (lane == 0) { red[0][wv] = s; red[1][wv] = ss; }
        __syncthreads();
        if (threadIdx.x == 0) {
            partial[blockIdx.x]              = red[0][0] + red[0][1] + red[0][2] + red[0][3];
            partial[GAT_BLOCKS + blockIdx.x] = red[1][0] + red[1][1] + red[1][2] + red[1][3];
        }
    }
}

// ---------------------------------------------------------------------------
// LN partial reduce + final normalize/project
// ---------------------------------------------------------------------------
__global__ void ln_reduce(const float* __restrict__ partial, float* __restrict__ stats) {
    float s = 0.f, ss = 0.f;
    for (int i = threadIdx.x; i < GAT_BLOCKS; i += 256) {
        s  += partial[i];
        ss += partial[GAT_BLOCKS + i];
    }
    s  = waveReduceSum(s);
    ss = waveReduceSum(ss);
    __shared__ float sm[2][4];
    if ((threadIdx.x & 63) == 0) {
        sm[0][threadIdx.x >> 6] = s;
        sm[1][threadIdx.x >> 6] = ss;
    }
    __syncthreads();
    if (threadIdx.x == 0) {
        stats[0] = sm[0][0] + sm[0][1] + sm[0][2] + sm[0][3];
        stats[1] = sm[1][0] + sm[1][1] + sm[1][2] + sm[1][3];
    }
}

__global__ void finalize(const float* __restrict__ x,
                         const float* __restrict__ stats,
                         const float* __restrict__ lnw,
                         const float* __restrict__ lnb,
                         const float* __restrict__ pw,
                         const float* __restrict__ pb,
                         float* __restrict__ out) {
    const int wave = (blockIdx.x * blockDim.x + threadIdx.x) >> 6;
    const int lane = threadIdx.x & 63;
    if (wave >= NN) return;
    const float inv_nd = 1.f / (float)(NN * D);
    const float mu  = stats[0] * inv_nd;
    const float var = stats[1] * inv_nd - mu * mu;
    const float rs = rsqrtf(var + EPS_LN);
    const float v = x[(size_t)wave * D + lane];
    const float xn = (v - mu) * rs * lnw[lane] + lnb[lane];
    const float c = waveReduceSum(xn * pw[lane]);
    if (lane == 0) out[wave] = c + pb[0];
}

extern "C" void kernel_launch(void* const* d_in, const int* in_sizes, int n_in,
                              void* d_out, int out_size, void* d_ws, size_t ws_size,
                              hipStream_t stream) {
    const float* x     = (const float*)d_in[0];
    const int*   ei    = (const int*)d_in[1];
    const float* Wsrc0 = (const float*)d_in[2];
    const float* Wdst0 = (const float*)d_in[3];
    const float* asrc0 = (const float*)d_in[4];
    const float* adst0 = (const float*)d_in[5];
    const float* b0    = (const float*)d_in[6];
    const float* linW0 = (const float*)d_in[7];
    const float* linb0 = (const float*)d_in[8];
    const float* W1    = (const float*)d_in[9];
    const float* asrc1 = (const float*)d_in[10];
    const float* adst1 = (const float*)d_in[11];
    const float* b1    = (const float*)d_in[12];
    const float* linW1 = (const float*)d_in[13];
    const float* linb1 = (const float*)d_in[14];
    const float* W2    = (const float*)d_in[15];
    const float* asrc2 = (const float*)d_in[16];
    const float* adst2 = (const float*)d_in[17];
    const float* b2    = (const float*)d_in[18];
    const float* linW2 = (const float*)d_in[19];
    const float* linb2 = (const float*)d_in[20];
    const float* lnw   = (const float*)d_in[21];
    const float* lnb   = (const float*)d_in[22];
    const float* pW    = (const float*)d_in[23];
    const float* pb    = (const float*)d_in[24];
    float* out = (float*)d_out;

    // workspace layout (pairs aliases A: pairs dead before layer-0 gemm writes A)
    int*  csr_src   = (int*)d_ws;                    // NBUK*BCAP
    int*  cnt       = csr_src + NBUK * BCAP;         // NN
    int*  row_start = cnt + NN;                      // NN
    int*  bcur      = row_start + NN;                // NBUK
    size_t off = (size_t)(NBUK * BCAP + 2 * NN + NBUK);
    off = (off + 3) & ~(size_t)3;                    // 16 B align
    float* A     = (float*)d_ws + off;               // NN*D floats
    int2*  pairs = (int2*)A;                         // NBUK*BCAP int2 (covers A)
    float* B     = A + (size_t)NBUK * BCAP * 2;      // after pairs extent
    __hip_bfloat16* P = (__hip_bfloat16*)(B + NN * D);   // NN*D bf16
    float* alpha_s = (float*)(P + NN * D);           // NN
    float* alpha_d = alpha_s + NN;                   // NN
    float* stats   = alpha_d + NN;                   // 2
    float* partial = stats + 2;                      // 2*GAT_BLOCKS
    unsigned short* wpk = (unsigned short*)(((uintptr_t)(partial + 2 * GAT_BLOCKS) + 15) & ~(uintptr_t)15);  // 12288 bf16

    const int elem_blocks = (NN * D) / 256;          // 12500

    // ---- build CSR by destination (bucket-strided; reused by all 3 layers) ----
    hipMemsetAsync(bcur, 0, NBUK * sizeof(int), stream);
    bucket_partition<<<NPB, 256, 0, stream>>>(ei, bcur, pairs);
    csr_finalize<<<NBUK, 256, 0, stream>>>(pairs, bcur, cnt, row_start, csr_src);

    // ---- layer 0 ----
    pack_w<<<48, 256, 0, stream>>>(Wsrc0, Wdst0, linW0, wpk, 3);
    gemm_mfma<3><<<GEMM_BLOCKS, 256, 0, stream>>>(x, wpk, asrc0, adst0, b0, linb0,
                                                  P, A, alpha_s, alpha_d);
    gat_node<true, false><<<GAT_BLOCKS, 256, 0, stream>>>(csr_src, row_start, cnt,
                                                          alpha_s, alpha_d, P, A, partial);

    // ---- layer 1 ----
    pack_w<<<32, 256, 0, stream>>>(W1, linW1, linW1, wpk, 2);
    gemm_mfma<2><<<GEMM_BLOCKS, 256, 0, stream>>>(A, wpk, asrc1, adst1, b1, linb1,
                                                  P, B, alpha_s, alpha_d);
    gat_node<true, false><<<GAT_BLOCKS, 256, 0, stream>>>(csr_src, row_start, cnt,
                                                          alpha_s, alpha_d, P, B, partial);

    // ---- layer 2 (fused LN partials) ----
    pack_w<<<32, 256, 0, stream>>>(W2, linW2, linW2, wpk, 2);
    gemm_mfma<2><<<GEMM_BLOCKS, 256, 0, stream>>>(B, wpk, asrc2, adst2, b2, linb2,
                                                  P, A, alpha_s, alpha_d);
    gat_node<false, true><<<GAT_BLOCKS, 256, 0, stream>>>(csr_src, row_start, cnt,
                                                          alpha_s, alpha_d, P, A, partial);

    // ---- graph layernorm + projection ----
    ln_reduce<<<1, 256, 0, stream>>>(partial, stats);
    finalize<<<elem_blocks, 256, 0, stream>>>(A, stats, lnw, lnb, pW, pb, out);
}

// Round 13
// 335.605 us; speedup vs baseline: 1.0404x; 1.0404x over previous
//
#include <hip/hip_runtime.h>
#include <hip/hip_bf16.h>

#define NN 50000
#define NE 1200000
#define D 64
#define NEG_SLOPE 0.2f
#define EPS_SM 1e-16f
#define EPS_LN 1e-5f
#define KMAX 4            // supports degree <= 256; Poisson(24) max over 50k nodes ~55
#define BSH 6             // 64 nodes per bucket
#define NBUK 782          // ceil(50000/64)
#define BCAP 2048         // fixed bucket capacity (mean 1536, +13 sigma)
#define BCAPSH 11
#define EPB 4096          // edges per partition block
#define NPB 293           // ceil(NE/EPB)
#define GEMM_BLOCKS 3125  // NN/16 exactly
#define GAT_BLOCKS 12500  // NN/4 exactly

typedef __attribute__((ext_vector_type(8))) short short8;
typedef __attribute__((ext_vector_type(4))) float float4v;

__device__ __forceinline__ float waveReduceSum(float v) {
    #pragma unroll
    for (int off = 32; off > 0; off >>= 1)
        v += __shfl_xor(v, off, 64);
    return v;
}
__device__ __forceinline__ float waveReduceMax(float v) {
    #pragma unroll
    for (int off = 32; off > 0; off >>= 1)
        v = fmaxf(v, __shfl_xor(v, off, 64));
    return v;
}
__device__ __forceinline__ float bflo(unsigned v) { return __uint_as_float(v << 16); }
__device__ __forceinline__ float bfhi(unsigned v) { return __uint_as_float(v & 0xffff0000u); }
__device__ __forceinline__ short f2bf_bits(float f) {
    __hip_bfloat16 b = __float2bfloat16(f);
    short v; __builtin_memcpy(&v, &b, 2);
    return v;
}

// ---------------------------------------------------------------------------
// Pack W (fp32 64x64 mats, concatenated channels) into bf16 B-fragment order.
// ---------------------------------------------------------------------------
__global__ void pack_w(const float* __restrict__ W0,
                       const float* __restrict__ W1m,
                       const float* __restrict__ W2m,
                       unsigned short* __restrict__ wpk, int nmats) {
    const int n = nmats * 4096;
    for (int idx = blockIdx.x * 256 + threadIdx.x; idx < n; idx += gridDim.x * 256) {
        const int j = idx & 7;
        const int lane = (idx >> 3) & 63;
        const int khtile = idx >> 9;
        const int kh = khtile & 1;
        const int tile = khtile >> 1;
        const int mat = tile >> 2;
        const int ch = (tile & 3) * 16 + (lane & 15);
        const int k = kh * 32 + (lane >> 4) * 8 + j;
        const float* W = (mat == 0) ? W0 : (mat == 1 ? W1m : W2m);
        wpk[idx] = (unsigned short)f2bf_bits(W[k * D + ch]);
    }
}

// ---------------------------------------------------------------------------
// MFMA projections: block = 16 nodes, A = X-tile (LDS, cvt to bf16 frags),
// B = pre-packed W frags. Epilogue: hp/agg stores + alpha dot-products.
// ---------------------------------------------------------------------------
template <int NMATS>
__global__ __launch_bounds__(256) void gemm_mfma(
                          const float* __restrict__ hin,
                          const unsigned short* __restrict__ wpk,
                          const float* __restrict__ avs,
                          const float* __restrict__ avd,
                          const float* __restrict__ bgat,
                          const float* __restrict__ blin,
                          __hip_bfloat16* __restrict__ hp,
                          float* __restrict__ agg,
                          float* __restrict__ alpha_s,
                          float* __restrict__ alpha_d) {
    constexpr int NT   = NMATS * 4;
    constexpr int NTPW = NT / 4;
    __shared__ float xt[16 * D];           // 4 KB
    __shared__ float ared[2][4][16];       // alpha partials [s/d][wave][node]

    const int t   = threadIdx.x;
    const int nb0 = blockIdx.x * 16;       // 3125*16 == 50000 exactly
    ((float4*)xt)[t] = ((const float4*)(hin + (size_t)nb0 * D))[t];
    __syncthreads();

    const int w    = t >> 6;
    const int lane = t & 63;
    const int mrow = lane & 15;            // A row within tile
    const int kq   = lane >> 4;            // quad

    short8 a[2];
    #pragma unroll
    for (int kh = 0; kh < 2; ++kh) {
        const float* xp = xt + mrow * D + kh * 32 + kq * 8;
        const float4 f0 = *(const float4*)(xp);
        const float4 f1 = *(const float4*)(xp + 4);
        a[kh][0] = f2bf_bits(f0.x); a[kh][1] = f2bf_bits(f0.y);
        a[kh][2] = f2bf_bits(f0.z); a[kh][3] = f2bf_bits(f0.w);
        a[kh][4] = f2bf_bits(f1.x); a[kh][5] = f2bf_bits(f1.y);
        a[kh][6] = f2bf_bits(f1.z); a[kh][7] = f2bf_bits(f1.w);
    }

    float4v acc[NTPW];
    #pragma unroll
    for (int i = 0; i < NTPW; ++i) {
        const int tile = w * NTPW + i;
        const short8 b0 = *(const short8*)(wpk + ((size_t)(tile * 2 + 0) * 64 + lane) * 8);
        const short8 b1 = *(const short8*)(wpk + ((size_t)(tile * 2 + 1) * 64 + lane) * 8);
        float4v c = {0.f, 0.f, 0.f, 0.f};
        c = __builtin_amdgcn_mfma_f32_16x16x32_bf16(a[0], b0, c, 0, 0, 0);
        c = __builtin_amdgcn_mfma_f32_16x16x32_bf16(a[1], b1, c, 0, 0, 0);
        acc[i] = c;
    }

    float psr[4] = {0.f, 0.f, 0.f, 0.f};
    float pdr[4] = {0.f, 0.f, 0.f, 0.f};
    #pragma unroll
    for (int i = 0; i < NTPW; ++i) {
        const int tile = w * NTPW + i;
        const int mat  = tile >> 2;                 // wave-uniform
        const int c64  = (tile & 3) * 16 + mrow;
        const float av_s = avs[c64], av_d = avd[c64];
        const float bias = blin[c64] + bgat[c64];
        #pragma unroll
        for (int r = 0; r < 4; ++r) {
            const int node = nb0 + kq * 4 + r;      // C/D: col=lane&15, row=quad*4+reg
            const float v = acc[i][r];
            if (mat == 0) {
                hp[(size_t)node * D + c64] = __float2bfloat16(v);
                psr[r] += v * av_s;
                if (NMATS == 2) pdr[r] += v * av_d;
            } else if (NMATS == 3 && mat == 1) {
                pdr[r] += v * av_d;
            } else {
                agg[(size_t)node * D + c64] = v + bias;
            }
        }
    }
    #pragma unroll
    for (int off = 1; off < 16; off <<= 1) {
        #pragma unroll
        for (int r = 0; r < 4; ++r) {
            psr[r] += __shfl_xor(psr[r], off, 64);
            pdr[r] += __shfl_xor(pdr[r], off, 64);
        }
    }
    if (mrow == 0) {
        #pragma unroll
        for (int r = 0; r < 4; ++r) {
            ared[0][w][kq * 4 + r] = psr[r];
            ared[1][w][kq * 4 + r] = pdr[r];
        }
    }
    __syncthreads();
    if (t < 16) {
        alpha_s[nb0 + t] = ared[0][0][t] + ared[0][1][t] + ared[0][2][t] + ared[0][3][t];
        alpha_d[nb0 + t] = ared[1][0][t] + ared[1][1][t] + ared[1][2][t] + ared[1][3][t];
    }
}

// ---------------------------------------------------------------------------
// CSR-by-destination: fixed-capacity bucket layout. pairs packed into one int:
// src (16 bits, NN < 65536) | bucket-local dst (6 bits) << 16.
// ---------------------------------------------------------------------------
__global__ __launch_bounds__(256) void bucket_partition(const int* __restrict__ ei,
                                                        int* __restrict__ bcur,
                                                        int* __restrict__ pairs) {
    __shared__ int h[NBUK];
    __shared__ int cur[NBUK];
    for (int i = threadIdx.x; i < NBUK; i += 256) h[i] = 0;
    __syncthreads();
    const int base = blockIdx.x * EPB;
    const int lim  = min(EPB, NE - base);
    for (int i = threadIdx.x; i < lim; i += 256)
        atomicAdd(&h[ei[NE + base + i] >> BSH], 1);
    __syncthreads();
    for (int i = threadIdx.x; i < NBUK; i += 256) {
        const int c = h[i];
        cur[i] = c ? atomicAdd(&bcur[i], c) : 0;
    }
    __syncthreads();
    for (int i = threadIdx.x; i < lim; i += 256) {
        const int s = ei[base + i];
        const int d = ei[NE + base + i];
        const int b = d >> BSH;
        const int pos = atomicAdd(&cur[b], 1);
        if (pos < BCAP) pairs[(b << BCAPSH) + pos] = s | ((d & 63) << 16);
    }
}

__global__ __launch_bounds__(256) void csr_finalize(const int* __restrict__ pairs,
                                                    const int* __restrict__ bcur,
                                                    int* __restrict__ cnt,
                                                    int* __restrict__ row_start,
                                                    int* __restrict__ csr_src) {
    __shared__ int ncnt[64];
    __shared__ int lsrc[BCAP];
    const int t = threadIdx.x;
    const int b = blockIdx.x;
    const int beg = b << BCAPSH;
    const int m = min(bcur[b], BCAP);
    const int nbase = b << BSH;
    if (t < 64) ncnt[t] = 0;
    __syncthreads();
    for (int i = t; i < m; i += 256)
        atomicAdd(&ncnt[pairs[beg + i] >> 16], 1);
    __syncthreads();
    if (t < 64) {
        const int v = ncnt[t];
        int inc = v;
        #pragma unroll
        for (int off = 1; off < 64; off <<= 1) {
            const int u = __shfl_up(inc, off, 64);
            if (t >= off) inc += u;
        }
        const int excl = inc - v;
        if (nbase + t < NN) {
            cnt[nbase + t] = v;
            row_start[nbase + t] = beg + excl;
        }
        ncnt[t] = excl;   // becomes bucket-local cursor
    }
    __syncthreads();
    for (int i = t; i < m; i += 256) {
        const int p = pairs[beg + i];
        const int pos = atomicAdd(&ncnt[p >> 16], 1);
        lsrc[pos] = p & 0xffff;
    }
    __syncthreads();
    for (int i = t; i < m; i += 256)
        csr_src[beg + i] = lsrc[i];
}

// ---------------------------------------------------------------------------
// Fused per-node GAT (round-11 layout: lanes 0-31 edge j, lanes 32-63 edge
// j+1, 2 bf16 channels per lane per uint). nt-hint on the streaming csr
// reads keeps the 6.4 MB hp table hot in L2; agg access left plain (nt
// stores defeated write-combining in round 12: WRITE 13.3 -> 14.8 MB).
// ---------------------------------------------------------------------------
template <bool DO_RELU, bool DO_STATS>
__global__ __launch_bounds__(256) void gat_node(
                         const int* __restrict__ csr_src,
                         const int* __restrict__ row_start,
                         const int* __restrict__ cnt,
                         const float* __restrict__ as,
                         const float* __restrict__ ad,
                         const __hip_bfloat16* __restrict__ hp,
                         float* __restrict__ agg,
                         float* __restrict__ partial) {
    __shared__ int2 esm[4][KMAX * 64];
    const int wv   = threadIdx.x >> 6;
    const int lane = threadIdx.x & 63;
    const int node = blockIdx.x * 4 + wv;   // NN == 4*GAT_BLOCKS: always valid
    const int snode = __builtin_amdgcn_readfirstlane(node);
    const int deg = cnt[snode];
    const int rs  = row_start[snode];
    const int half = lane >> 5;
    const int c2   = lane & 31;
    float2 acc = make_float2(0.f, 0.f);
    if (deg > 0) {
        const float ad_d = ad[snode];
        int   sr[KMAX];
        float ea[KMAX];
        float mx = -INFINITY;
        #pragma unroll
        for (int k = 0; k < KMAX; ++k) {
            const int j = k * 64 + lane;
            const bool valid = j < deg;
            const int s = valid ? __builtin_nontemporal_load(csr_src + rs + j) : 0;
            float a = valid ? (as[s] + ad_d) : -INFINITY;
            a = (a >= 0.f) ? a : NEG_SLOPE * a;
            sr[k] = s;
            ea[k] = a;
            mx = fmaxf(mx, a);
        }
        mx = waveReduceMax(mx);
        float sum = 0.f;
        #pragma unroll
        for (int k = 0; k < KMAX; ++k) {
            float e = __expf(ea[k] - mx);
            e = (k * 64 + lane < deg) ? e : 0.f;
            ea[k] = e;
            sum += e;
        }
        sum = waveReduceSum(sum);
        const float inv = 1.f / (sum + EPS_SM);
        #pragma unroll
        for (int k = 0; k < KMAX; ++k) {
            if (k * 64 < deg)            // wave-uniform; lanes >= deg write {0,0}
                esm[wv][k * 64 + lane] = make_int2(sr[k] * 32, __float_as_int(ea[k] * inv));
        }
        const unsigned* hp32 = (const unsigned*)hp;
        const int jmax = (deg + 1) & ~1;
        float2 a0 = make_float2(0.f, 0.f), a1 = make_float2(0.f, 0.f);
        int j = 0;
        for (; j + 4 <= jmax; j += 4) {
            const int2 p0 = esm[wv][j + 0 + half];
            const int2 p1 = esm[wv][j + 2 + half];
            const unsigned v0 = hp32[p0.x + c2];
            const unsigned v1 = hp32[p1.x + c2];
            const float w0 = __int_as_float(p0.y), w1 = __int_as_float(p1.y);
            a0.x = fmaf(w0, bflo(v0), a0.x);
            a0.y = fmaf(w0, bfhi(v0), a0.y);
            a1.x = fmaf(w1, bflo(v1), a1.x);
            a1.y = fmaf(w1, bfhi(v1), a1.y);
        }
        for (; j < jmax; j += 2) {
            const int2 p = esm[wv][j + half];
            const unsigned v = hp32[p.x + c2];
            const float w = __int_as_float(p.y);
            a0.x = fmaf(w, bflo(v), a0.x);
            a0.y = fmaf(w, bfhi(v), a0.y);
        }
        acc.x = a0.x + a1.x;
        acc.y = a0.y + a1.y;
    }
    acc.x += __shfl_xor(acc.x, 32, 64);
    acc.y += __shfl_xor(acc.y, 32, 64);

    float2 r2 = make_float2(0.f, 0.f);
    if (half == 0) {
        const float2 g = *(const float2*)(agg + (size_t)node * D + 2 * c2);
        r2.x = g.x + acc.x;
        r2.y = g.y + acc.y;
        if (DO_RELU) { r2.x = fmaxf(r2.x, 0.f); r2.y = fmaxf(r2.y, 0.f); }
        *(float2*)(agg + (size_t)node * D + 2 * c2) = r2;
    }
    if (DO_STATS) {
        float s  = r2.x + r2.y;
        float ss = r2.x * r2.x + r2.y * r2.y;
        s  = waveReduceSum(s);
        ss = waveReduceSum(ss);
        __shared__ float red[2][4];
        if (lane == 0) { red[0][wv] = s; red[1][wv] = ss; }
        __syncthreads();
        if (threadIdx.x == 0) {
            partial[blockIdx.x]              = red[0][0] + red[0][1] + red[0][2] + red[0][3];
            partial[GAT_BLOCKS + blockIdx.x] = red[1][0] + red[1][1] + red[1][2] + red[1][3];
        }
    }
}

// ---------------------------------------------------------------------------
// LN partial reduce + final normalize/project
// ---------------------------------------------------------------------------
__global__ void ln_reduce(const float* __restrict__ partial, float* __restrict__ stats) {
    float s = 0.f, ss = 0.f;
    for (int i = threadIdx.x; i < GAT_BLOCKS; i += 256) {
        s  += partial[i];
        ss += partial[GAT_BLOCKS + i];
    }
    s  = waveReduceSum(s);
    ss = waveReduceSum(ss);
    __shared__ float sm[2][4];
    if ((threadIdx.x & 63) == 0) {
        sm[0][threadIdx.x >> 6] = s;
        sm[1][threadIdx.x >> 6] = ss;
    }
    __syncthreads();
    if (threadIdx.x == 0) {
        stats[0] = sm[0][0] + sm[0][1] + sm[0][2] + sm[0][3];
        stats[1] = sm[1][0] + sm[1][1] + sm[1][2] + sm[1][3];
    }
}

__global__ void finalize(const float* __restrict__ x,
                         const float* __restrict__ stats,
                         const float* __restrict__ lnw,
                         const float* __restrict__ lnb,
                         const float* __restrict__ pw,
                         const float* __restrict__ pb,
                         float* __restrict__ out) {
    const int wave = (blockIdx.x * blockDim.x + threadIdx.x) >> 6;
    const int lane = threadIdx.x & 63;
    if (wave >= NN) return;
    const float inv_nd = 1.f / (float)(NN * D);
    const float mu  = stats[0] * inv_nd;
    const float var = stats[1] * inv_nd - mu * mu;
    const float rs = rsqrtf(var + EPS_LN);
    const float v = x[(size_t)wave * D + lane];
    const float xn = (v - mu) * rs * lnw[lane] + lnb[lane];
    const float c = waveReduceSum(xn * pw[lane]);
    if (lane == 0) out[wave] = c + pb[0];
}

extern "C" void kernel_launch(void* const* d_in, const int* in_sizes, int n_in,
                              void* d_out, int out_size, void* d_ws, size_t ws_size,
                              hipStream_t stream) {
    const float* x     = (const float*)d_in[0];
    const int*   ei    = (const int*)d_in[1];
    const float* Wsrc0 = (const float*)d_in[2];
    const float* Wdst0 = (const float*)d_in[3];
    const float* asrc0 = (const float*)d_in[4];
    const float* adst0 = (const float*)d_in[5];
    const float* b0    = (const float*)d_in[6];
    const float* linW0 = (const float*)d_in[7];
    const float* linb0 = (const float*)d_in[8];
    const float* W1    = (const float*)d_in[9];
    const float* asrc1 = (const float*)d_in[10];
    const float* adst1 = (const float*)d_in[11];
    const float* b1    = (const float*)d_in[12];
    const float* linW1 = (const float*)d_in[13];
    const float* linb1 = (const float*)d_in[14];
    const float* W2    = (const float*)d_in[15];
    const float* asrc2 = (const float*)d_in[16];
    const float* adst2 = (const float*)d_in[17];
    const float* b2    = (const float*)d_in[18];
    const float* linW2 = (const float*)d_in[19];
    const float* linb2 = (const float*)d_in[20];
    const float* lnw   = (const float*)d_in[21];
    const float* lnb   = (const float*)d_in[22];
    const float* pW    = (const float*)d_in[23];
    const float* pb    = (const float*)d_in[24];
    float* out = (float*)d_out;

    // workspace layout (pairs aliases A: pairs dead before layer-0 gemm writes A)
    int*  csr_src   = (int*)d_ws;                    // NBUK*BCAP
    int*  cnt       = csr_src + NBUK * BCAP;         // NN
    int*  row_start = cnt + NN;                      // NN
    int*  bcur      = row_start + NN;                // NBUK
    size_t off = (size_t)(NBUK * BCAP + 2 * NN + NBUK);
    off = (off + 3) & ~(size_t)3;                    // 16 B align
    float* A     = (float*)d_ws + off;               // NN*D floats
    int*   pairs = (int*)A;                          // NBUK*BCAP ints (covers A)
    float* B     = A + (size_t)NN * D;               // NN*D floats
    __hip_bfloat16* P = (__hip_bfloat16*)(B + NN * D);   // NN*D bf16
    float* alpha_s = (float*)(P + NN * D);           // NN
    float* alpha_d = alpha_s + NN;                   // NN
    float* stats   = alpha_d + NN;                   // 2
    float* partial = stats + 2;                      // 2*GAT_BLOCKS
    unsigned short* wpk = (unsigned short*)(((uintptr_t)(partial + 2 * GAT_BLOCKS) + 15) & ~(uintptr_t)15);  // 12288 bf16

    const int elem_blocks = (NN * D) / 256;          // 12500

    // ---- build CSR by destination (bucket-strided; reused by all 3 layers) ----
    hipMemsetAsync(bcur, 0, NBUK * sizeof(int), stream);
    bucket_partition<<<NPB, 256, 0, stream>>>(ei, bcur, pairs);
    csr_finalize<<<NBUK, 256, 0, stream>>>(pairs, bcur, cnt, row_start, csr_src);

    // ---- layer 0 ----
    pack_w<<<48, 256, 0, stream>>>(Wsrc0, Wdst0, linW0, wpk, 3);
    gemm_mfma<3><<<GEMM_BLOCKS, 256, 0, stream>>>(x, wpk, asrc0, adst0, b0, linb0,
                                                  P, A, alpha_s, alpha_d);
    gat_node<true, false><<<GAT_BLOCKS, 256, 0, stream>>>(csr_src, row_start, cnt,
                                                          alpha_s, alpha_d, P, A, partial);

    // ---- layer 1 ----
    pack_w<<<32, 256, 0, stream>>>(W1, linW1, linW1, wpk, 2);
    gemm_mfma<2><<<GEMM_BLOCKS, 256, 0, stream>>>(A, wpk, asrc1, adst1, b1, linb1,
                                                  P, B, alpha_s, alpha_d);
    gat_node<true, false><<<GAT_BLOCKS, 256, 0, stream>>>(csr_src, row_start, cnt,
                                                          alpha_s, alpha_d, P, B, partial);

    // ---- layer 2 (fused LN partials) ----
    pack_w<<<32, 256, 0, stream>>>(W2, linW2, linW2, wpk, 2);
    gemm_mfma<2><<<GEMM_BLOCKS, 256, 0, stream>>>(B, wpk, asrc2, adst2, b2, linb2,
                                                  P, A, alpha_s, alpha_d);
    gat_node<false, true><<<GAT_BLOCKS, 256, 0, stream>>>(csr_src, row_start, cnt,
                                                          alpha_s, alpha_d, P, A, partial);

    // ---- graph layernorm + projection ----
    ln_reduce<<<1, 256, 0, stream>>>(partial, stats);
    finalize<<<elem_blocks, 256, 0, stream>>>(A, stats, lnw, lnb, pW, pb, out);
}